// Round 1
// baseline (73.545 us; speedup 1.0000x reference)
//
#include <hip/hip_runtime.h>
#include <hip/hip_bf16.h>
#include <math.h>

#define BS 8192
#define D 128
#define NROWS 16384              // 2*BS
#define BM 128
#define BN 128
#define COLS_PER_BLOCK 2048
#define NTILES (COLS_PER_BLOCK / BN)      // 16
#define NSPLIT (NROWS / COLS_PER_BLOCK)   // 8
#define NPART (NSPLIT * 2)                // 16 partial sum buffers

typedef __bf16 bf16x8 __attribute__((ext_vector_type(8)));
typedef float f32x4 __attribute__((ext_vector_type(4)));

#define SQRT_LOG2E 1.2011224087864498f
#define LN2F 0.6931471805599453f

#if __has_builtin(__builtin_amdgcn_exp2f)
#define EXP2F(x) __builtin_amdgcn_exp2f(x)
#else
#define EXP2F(x) exp2f(x)
#endif

__device__ __forceinline__ void gload_lds16(const void* g, void* l) {
  __builtin_amdgcn_global_load_lds(
      (const __attribute__((address_space(1))) void*)g,
      (__attribute__((address_space(3))) void*)l, 16, 0, 0);
}

// Kernel 1: row norms + pre-scaled bf16 conversion.
// cat rows [0,8192) = noise, [8192,16384) = f. Each row scaled by sqrt(log2e)/||row||
// so the later MFMA dot directly yields cos_sim * log2(e).
__global__ __launch_bounds__(256) void nrm_cvt(const float* __restrict__ f,
                                               const float* __restrict__ noise,
                                               __hip_bfloat16* __restrict__ catb) {
  const int lane = threadIdx.x & 63;
  const int wv = threadIdx.x >> 6;
  const int row = blockIdx.x * 4 + wv;
  const float* src = (row < BS) ? (noise + (size_t)row * D) : (f + (size_t)(row - BS) * D);
  float2 v = ((const float2*)src)[lane];
  float ss = v.x * v.x + v.y * v.y;
#pragma unroll
  for (int m = 1; m <= 32; m <<= 1) ss += __shfl_xor(ss, m, 64);
  float s = SQRT_LOG2E / sqrtf(ss);
  float2 sv;
  sv.x = v.x * s;
  sv.y = v.y * s;
  __hip_bfloat162 b2 = __float22bfloat162_rn(sv);
  ((__hip_bfloat162*)(catb + (size_t)row * D))[lane] = b2;
}

// Kernel 2: fused GEMM + exp + row-sum with diagonal exclusion.
// Block: 256 threads = 4 waves (2x2). Block owns rows [mb*128, +128) x cols [nb*2048, +2048).
// K=128 in registers; B tiles double-buffered in LDS (swizzled src -> conflict-free ds_read_b128).
__global__ __launch_bounds__(256) void infonce_main(
    const __hip_bfloat16* __restrict__ catb,
    float* __restrict__ ws_neg, float* __restrict__ ws_pos) {
  __shared__ __align__(16) char lds[2][BN * D * 2];  // 2 x 32 KiB
  const int tid = threadIdx.x;
  const int lane = tid & 63;
  const int w = tid >> 6;
  const int wr = w >> 1, wc = w & 1;
  const int l15 = lane & 15, l4 = lane >> 4;
  const int nb = blockIdx.x, mb = blockIdx.y;
  const int mrow0 = mb * BM;
  const int col0 = nb * COLS_PER_BLOCK;
  const char* catbytes = (const char*)catb;

  // staging constants (per thread): chunk col / swizzled k offset
  const int c16 = tid >> 4;  // 0..15
  const int kswz = ((tid & 15) ^ (c16 & 7)) << 4;

  auto stage = [&](int bufidx, int t) {
    const char* gb = catbytes + ((size_t)(col0 + t * BN)) * (D * 2);
#pragma unroll
    for (int i = 0; i < 8; i++) {
      const int col = i * 16 + c16;
      const char* src = gb + col * 256 + kswz;           // pre-swizzled global source
      char* dst = &lds[bufidx][(i * 256 + w * 64) * 16]; // wave-uniform linear LDS dest
      gload_lds16(src, dst);
    }
  };

  // A fragments: this wave's 64 f-rows, all of K, in registers.
  bf16x8 a[4][4];
  {
    const char* fb = catbytes + (size_t)BS * (D * 2);
#pragma unroll
    for (int rf = 0; rf < 4; rf++) {
      const char* p = fb + (size_t)(mrow0 + wr * 64 + rf * 16 + l15) * 256 + l4 * 16;
#pragma unroll
      for (int kk = 0; kk < 4; kk++) a[rf][kk] = *(const bf16x8*)(p + kk * 64);
    }
  }

  // ds_read offsets (per-lane constants; XOR swizzle matches staging)
  const int dsbase = l15 * 256;
  int koff[4];
#pragma unroll
  for (int kk = 0; kk < 4; kk++) koff[kk] = ((kk * 64 + l4 * 16) ^ ((lane & 7) << 4));

  float rowsum[16];
#pragma unroll
  for (int i = 0; i < 16; i++) rowsum[i] = 0.f;

  stage(0, 0);
  __syncthreads();

  for (int t = 0; t < NTILES; t++) {
    if (t + 1 < NTILES) stage((t + 1) & 1, t + 1);  // prefetch next tile
    const char* buf = lds[t & 1];
    const int gc0 = col0 + t * BN;

    f32x4 acc[4][4];
    const f32x4 z = {0.f, 0.f, 0.f, 0.f};
#pragma unroll
    for (int rf = 0; rf < 4; rf++)
#pragma unroll
      for (int cf = 0; cf < 4; cf++) acc[rf][cf] = z;

#pragma unroll
    for (int kk = 0; kk < 4; kk++) {
      bf16x8 b4[4];
#pragma unroll
      for (int cf = 0; cf < 4; cf++)
        b4[cf] = *(const bf16x8*)(buf + wc * 16384 + cf * 4096 + dsbase + koff[kk]);
#pragma unroll
      for (int rf = 0; rf < 4; rf++)
#pragma unroll
        for (int cf = 0; cf < 4; cf++)
          acc[rf][cf] = __builtin_amdgcn_mfma_f32_16x16x32_bf16(a[rf][kk], b4[cf],
                                                                acc[rf][cf], 0, 0, 0);
    }

    // epilogue: acc holds sim*log2e. exp2 + accumulate row sums.
    const bool dPos = (gc0 == mrow0);         // cols == f-row ids -> m[i,i] (pos)
    const bool dSelf = (gc0 == mrow0 + BS);   // cols == i+bs      -> self-sim
    if (!dPos && !dSelf) {
#pragma unroll
      for (int rf = 0; rf < 4; rf++)
#pragma unroll
        for (int cf = 0; cf < 4; cf++)
#pragma unroll
          for (int r = 0; r < 4; r++) rowsum[rf * 4 + r] += EXP2F(acc[rf][cf][r]);
    } else {
#pragma unroll
      for (int rf = 0; rf < 4; rf++)
#pragma unroll
        for (int cf = 0; cf < 4; cf++)
#pragma unroll
          for (int r = 0; r < 4; r++) {
            const int lr = wr * 64 + rf * 16 + l4 * 4 + r;
            const int lc = wc * 64 + cf * 16 + l15;
            const float t2 = acc[rf][cf][r];
            const bool ex = (lr == lc);
            if (dPos && ex) ws_pos[mrow0 + lr] = t2;  // store sim_pos*log2e
            rowsum[rf * 4 + r] += ex ? 0.f : EXP2F(t2);
          }
    }
    __syncthreads();
  }

  // reduce across the 16 lanes sharing each row (xor over low 4 lane bits)
#pragma unroll
  for (int s = 0; s < 16; s++) {
    float v = rowsum[s];
    v += __shfl_xor(v, 1, 64);
    v += __shfl_xor(v, 2, 64);
    v += __shfl_xor(v, 4, 64);
    v += __shfl_xor(v, 8, 64);
    rowsum[s] = v;
  }
  if (l15 == 0) {
    float* dst = ws_neg + (size_t)(nb * 2 + wc) * BS + mrow0 + wr * 64;
#pragma unroll
    for (int rf = 0; rf < 4; rf++)
#pragma unroll
      for (int r = 0; r < 4; r++) dst[rf * 16 + l4 * 4 + r] = rowsum[rf * 4 + r];
  }
}

// Kernel 3: combine partials, per-row loss, mean.
__global__ __launch_bounds__(256) void finalize(const float* __restrict__ ws_neg,
                                                const float* __restrict__ ws_pos,
                                                float* __restrict__ out) {
  __shared__ float red[256];
  float local = 0.f;
  for (int row = threadIdx.x; row < BS; row += 256) {
    float neg = 0.f;
#pragma unroll
    for (int p = 0; p < NPART; p++) neg += ws_neg[(size_t)p * BS + row];
    // loss = log(neg_sum + eps) - sim_pos ; sim_pos = (sim*log2e)*ln2
    local += logf(neg + 1e-6f) - ws_pos[row] * LN2F;
  }
  red[threadIdx.x] = local;
  __syncthreads();
#pragma unroll
  for (int s = 128; s > 0; s >>= 1) {
    if ((int)threadIdx.x < s) red[threadIdx.x] += red[threadIdx.x + s];
    __syncthreads();
  }
  if (threadIdx.x == 0) out[0] = red[0] * (1.f / BS);
}

extern "C" void kernel_launch(void* const* d_in, const int* in_sizes, int n_in,
                              void* d_out, int out_size, void* d_ws, size_t ws_size,
                              hipStream_t stream) {
  const float* f = (const float*)d_in[0];
  const float* noise = (const float*)d_in[1];
  char* ws = (char*)d_ws;
  __hip_bfloat16* catb = (__hip_bfloat16*)ws;                 // 4 MiB
  float* ws_pos = (float*)(ws + (size_t)NROWS * D * 2);       // 32 KiB
  float* ws_neg = ws_pos + BS;                                // 512 KiB

  nrm_cvt<<<NROWS / 4, 256, 0, stream>>>(f, noise, catb);
  dim3 grid(NSPLIT, BS / BM);
  infonce_main<<<grid, 256, 0, stream>>>(catb, ws_neg, ws_pos);
  finalize<<<1, 256, 0, stream>>>(ws_neg, ws_pos, (float*)d_out);
}